// Round 1
// baseline (348.036 us; speedup 1.0000x reference)
//
#include <hip/hip_runtime.h>
#include <hip/hip_bf16.h>
#include <math.h>

#define N 512
#define D 128
#define DD (D*D)
#define ND (N*D)

__device__ __forceinline__ float sigmoidf_(float x) { return 1.f / (1.f + expf(-x)); }

// ---------------- transpose W_mem layers 1..3 for backward ----------------
__global__ void k_transpose(const float* __restrict__ W_mem, float* __restrict__ WT) {
    int idx = blockIdx.x * 256 + threadIdx.x;      // 0 .. 3*128*128-1
    int l = idx / DD;                              // 0..2  -> layer l+1
    int r = idx % DD;
    int i = r / D;
    int j = r % D;
    // WT[l][i*D + j] = W_mem[l+1][j*D + i]
    WT[idx] = W_mem[(l + 1) * DD + j * D + i];
}

// ---------------- phase 1: per-token scalars, k/v/q, MLP fwd+bwd ----------------
__global__ __launch_bounds__(128) void k_phase1(
    const float* __restrict__ seq, const float* __restrict__ W_mem,
    const float* __restrict__ W_q, const float* __restrict__ W_kv,
    const float* __restrict__ W_mom, const float* __restrict__ W_step,
    const float* __restrict__ W_decay, const float* __restrict__ WT,
    float* __restrict__ Q, float* __restrict__ INS, float* __restrict__ ES,
    float* __restrict__ am, float* __restrict__ dec)
{
    __shared__ float s_seq[D];
    __shared__ float sm0[D], sm1[D];
    __shared__ float s_red[6];
    __shared__ float s_lr;

    const int t = blockIdx.x;
    const int tid = threadIdx.x;

    float sv = seq[t * D + tid];
    s_seq[tid] = sv;

    // three scalar dot products: lr, am, decay
    float p0 = sv * W_step[tid];
    float p1 = sv * W_mom[tid];
    float p2 = sv * W_decay[tid];
#pragma unroll
    for (int off = 32; off > 0; off >>= 1) {
        p0 += __shfl_down(p0, off);
        p1 += __shfl_down(p1, off);
        p2 += __shfl_down(p2, off);
    }
    if ((tid & 63) == 0) {
        int w = tid >> 6;
        s_red[w * 3 + 0] = p0;
        s_red[w * 3 + 1] = p1;
        s_red[w * 3 + 2] = p2;
    }
    __syncthreads();
    if (tid == 0) {
        float lr = s_red[0] + s_red[3];
        float amv = s_red[1] + s_red[4];
        float dv = s_red[2] + s_red[5];
        s_lr = lr;
        am[t] = amv;
        dec[t] = 1.f - sigmoidf_(dv);
    }
    __syncthreads();
    const float lr = s_lr;

    // k, v, q  (coalesced across tid: consecutive columns)
    float kj = 0.f, vj = 0.f, qj = 0.f;
#pragma unroll 4
    for (int i = 0; i < D; i++) {
        float si = s_seq[i];
        kj += si * W_kv[i * 2 * D + tid];
        vj += si * W_kv[i * 2 * D + D + tid];
        qj += si * W_q[i * D + tid];
    }
    Q[t * D + tid] = qj;
    INS[0 * ND + t * D + tid] = kj;
    sm0[tid] = kj;
    __syncthreads();

    // forward MLP, keep pre-activations in registers
    float* cur = sm0;
    float* nxt = sm1;
    float hreg[4];
    float pred = 0.f;
    for (int l = 0; l < 4; l++) {
        const float* Wl = W_mem + l * DD + tid;
        float y = 0.f;
#pragma unroll 4
        for (int i = 0; i < D; i++) y += cur[i] * Wl[i * D];
        hreg[l] = y;
        if (l < 3) {
            float a = y * sigmoidf_(y);
            nxt[tid] = a;
            INS[(l + 1) * ND + t * D + tid] = a;
        } else {
            pred = y;
        }
        float* tmp = cur; cur = nxt; nxt = tmp;
        __syncthreads();
    }

    // e3 = -lr * dL/dpred = -lr * 2*(pred - v)/D
    float e = -lr * (2.f / (float)D) * (pred - vj);
    ES[3 * ND + t * D + tid] = e;
    cur[tid] = e;
    __syncthreads();

    // backward: e_{l-1} = (e_l @ W_l^T) * silu'(h_{l-1})
    for (int l = 3; l >= 1; l--) {
        const float* Wt = WT + (l - 1) * DD + tid;
        float g = 0.f;
#pragma unroll 4
        for (int i = 0; i < D; i++) g += cur[i] * Wt[i * D];
        float h = hreg[l - 1];
        float sg = sigmoidf_(h);
        float dsilu = sg * (1.f + h * (1.f - sg));
        float e2 = g * dsilu;
        ES[(l - 1) * ND + t * D + tid] = e2;
        nxt[tid] = e2;
        float* tmp = cur; cur = nxt; nxt = tmp;
        __syncthreads();
    }
}

// ---------------- phase 2: beta coefficient matrix (double scalar scan) ----------------
__global__ void k_beta(const float* __restrict__ am, const float* __restrict__ dec,
                       float* __restrict__ beta)
{
    int s = blockIdx.x * 256 + threadIdx.x;
    if (s >= N) return;
    for (int t = 0; t < s; t++) beta[t * N + s] = 0.f;
    beta[s * N + s] = 1.f;
    float A = 1.f, b = 1.f;
    for (int t = s + 1; t < N; t++) {
        A *= am[t];
        b = dec[t] * b + A;
        beta[t * N + s] = b;
    }
}

// ---------------- phase 3: one retrieval layer (attention-shaped) ----------------
__global__ __launch_bounds__(128) void k_phase3(
    const float* __restrict__ Xin, float* __restrict__ Xout,
    const float* __restrict__ Wl, const float* __restrict__ INSl,
    const float* __restrict__ ESl, const float* __restrict__ beta,
    int act)
{
    __shared__ float s_x[D];
    __shared__ float s_c[N];

    const int t = blockIdx.x;
    const int tid = threadIdx.x;

    s_x[tid] = Xin[t * D + tid];
    __syncthreads();

    // c_s = beta[t,s] * (x . in_s) for s <= t
    for (int s = tid; s <= t; s += 128) {
        const float* ip = INSl + s * D;
        float acc = 0.f;
#pragma unroll 8
        for (int i = 0; i < D; i++) acc += s_x[i] * ip[i];
        s_c[s] = beta[t * N + s] * acc;
    }
    __syncthreads();

    // y_j = x @ W[:,j] + sum_s c_s * e_s[j]
    float y = 0.f;
    const float* wp = Wl + tid;
#pragma unroll 4
    for (int i = 0; i < D; i++) y += s_x[i] * wp[i * D];
    const float* ep = ESl + tid;
    for (int s = 0; s <= t; s++) y += s_c[s] * ep[s * D];

    if (act) y = y * sigmoidf_(y);
    Xout[t * D + tid] = y;
}

extern "C" void kernel_launch(void* const* d_in, const int* in_sizes, int n_in,
                              void* d_out, int out_size, void* d_ws, size_t ws_size,
                              hipStream_t stream) {
    const float* seq     = (const float*)d_in[0];
    const float* W_mem   = (const float*)d_in[1];
    const float* W_q     = (const float*)d_in[2];
    const float* W_kv    = (const float*)d_in[3];
    const float* W_mom   = (const float*)d_in[4];
    const float* W_step  = (const float*)d_in[5];
    const float* W_decay = (const float*)d_in[6];
    float* out = (float*)d_out;

    float* ws   = (float*)d_ws;
    float* am   = ws;                  // N
    float* dec  = am + N;              // N
    float* Q    = dec + N;             // N*D
    float* INS  = Q + ND;              // 4*N*D
    float* ES   = INS + 4 * ND;        // 4*N*D
    float* beta = ES + 4 * ND;         // N*N
    float* X    = beta + N * N;        // N*D
    float* WT   = X + ND;              // 3*D*D

    k_transpose<<<192, 256, 0, stream>>>(W_mem, WT);
    k_phase1<<<N, D, 0, stream>>>(seq, W_mem, W_q, W_kv, W_mom, W_step, W_decay,
                                  WT, Q, INS, ES, am, dec);
    k_beta<<<2, 256, 0, stream>>>(am, dec, beta);

    k_phase3<<<N, D, 0, stream>>>(Q, X, W_mem + 0 * DD, INS + 0 * ND, ES + 0 * ND, beta, 1);
    k_phase3<<<N, D, 0, stream>>>(X, X, W_mem + 1 * DD, INS + 1 * ND, ES + 1 * ND, beta, 1);
    k_phase3<<<N, D, 0, stream>>>(X, X, W_mem + 2 * DD, INS + 2 * ND, ES + 2 * ND, beta, 1);
    k_phase3<<<N, D, 0, stream>>>(X, out, W_mem + 3 * DD, INS + 3 * ND, ES + 3 * ND, beta, 0);
}

// Round 2
// 298.695 us; speedup vs baseline: 1.1652x; 1.1652x over previous
//
#include <hip/hip_runtime.h>
#include <hip/hip_bf16.h>
#include <math.h>

#define N 512
#define D 128
#define DD (D*D)
#define ND (N*D)

__device__ __forceinline__ float sigmoidf_(float x) { return 1.f / (1.f + expf(-x)); }

// ---------------- transpose W_mem layers 1..3 for backward ----------------
__global__ void k_transpose(const float* __restrict__ W_mem, float* __restrict__ WT) {
    int idx = blockIdx.x * 256 + threadIdx.x;      // 0 .. 3*128*128-1
    int l = idx / DD;                              // 0..2  -> layer l+1
    int r = idx % DD;
    int i = r / D;
    int j = r % D;
    WT[idx] = W_mem[(l + 1) * DD + j * D + i];
}

// ---------------- phase 1: per-token scalars, k/v/q, MLP fwd+bwd ----------------
__global__ __launch_bounds__(128) void k_phase1(
    const float* __restrict__ seq, const float* __restrict__ W_mem,
    const float* __restrict__ W_q, const float* __restrict__ W_kv,
    const float* __restrict__ W_mom, const float* __restrict__ W_step,
    const float* __restrict__ W_decay, const float* __restrict__ WT,
    float* __restrict__ Q, float* __restrict__ INS, float* __restrict__ ES,
    float* __restrict__ am, float* __restrict__ dec)
{
    __shared__ float s_seq[D];
    __shared__ float sm0[D], sm1[D];
    __shared__ float s_red[6];
    __shared__ float s_lr;

    const int t = blockIdx.x;
    const int tid = threadIdx.x;

    float sv = seq[t * D + tid];
    s_seq[tid] = sv;

    float p0 = sv * W_step[tid];
    float p1 = sv * W_mom[tid];
    float p2 = sv * W_decay[tid];
#pragma unroll
    for (int off = 32; off > 0; off >>= 1) {
        p0 += __shfl_down(p0, off);
        p1 += __shfl_down(p1, off);
        p2 += __shfl_down(p2, off);
    }
    if ((tid & 63) == 0) {
        int w = tid >> 6;
        s_red[w * 3 + 0] = p0;
        s_red[w * 3 + 1] = p1;
        s_red[w * 3 + 2] = p2;
    }
    __syncthreads();
    if (tid == 0) {
        float lr = s_red[0] + s_red[3];
        float amv = s_red[1] + s_red[4];
        float dv = s_red[2] + s_red[5];
        s_lr = lr;
        am[t] = amv;
        dec[t] = 1.f - sigmoidf_(dv);
    }
    __syncthreads();
    const float lr = s_lr;

    float kj = 0.f, vj = 0.f, qj = 0.f;
#pragma unroll 4
    for (int i = 0; i < D; i++) {
        float si = s_seq[i];
        kj += si * W_kv[i * 2 * D + tid];
        vj += si * W_kv[i * 2 * D + D + tid];
        qj += si * W_q[i * D + tid];
    }
    Q[t * D + tid] = qj;
    INS[0 * ND + t * D + tid] = kj;
    sm0[tid] = kj;
    __syncthreads();

    float* cur = sm0;
    float* nxt = sm1;
    float hreg[4];
    float pred = 0.f;
    for (int l = 0; l < 4; l++) {
        const float* Wl = W_mem + l * DD + tid;
        float y = 0.f;
#pragma unroll 4
        for (int i = 0; i < D; i++) y += cur[i] * Wl[i * D];
        hreg[l] = y;
        if (l < 3) {
            float a = y * sigmoidf_(y);
            nxt[tid] = a;
            INS[(l + 1) * ND + t * D + tid] = a;
        } else {
            pred = y;
        }
        float* tmp = cur; cur = nxt; nxt = tmp;
        __syncthreads();
    }

    float e = -lr * (2.f / (float)D) * (pred - vj);
    ES[3 * ND + t * D + tid] = e;
    cur[tid] = e;
    __syncthreads();

    for (int l = 3; l >= 1; l--) {
        const float* Wt = WT + (l - 1) * DD + tid;
        float g = 0.f;
#pragma unroll 4
        for (int i = 0; i < D; i++) g += cur[i] * Wt[i * D];
        float h = hreg[l - 1];
        float sg = sigmoidf_(h);
        float dsilu = sg * (1.f + h * (1.f - sg));
        float e2 = g * dsilu;
        ES[(l - 1) * ND + t * D + tid] = e2;
        nxt[tid] = e2;
        float* tmp = cur; cur = nxt; nxt = tmp;
        __syncthreads();
    }
}

// ---------------- phase 2a: log-space prefix scans (1 block, 512 threads) ----------------
__global__ __launch_bounds__(512) void k_logscan(
    const float* __restrict__ am, const float* __restrict__ dec,
    double* __restrict__ LA, double* __restrict__ LDp, int* __restrict__ NC)
{
    __shared__ double sa[N], sd[N];
    __shared__ int sn[N];
    const int t = threadIdx.x;
    float a = am[t];
    float d = dec[t];
    sa[t] = log((double)fmaxf(fabsf(a), 1e-38f));
    sd[t] = log((double)fmaxf(d, 1e-38f));
    sn[t] = (a < 0.f) ? 1 : 0;
    __syncthreads();
    for (int off = 1; off < N; off <<= 1) {
        double va = 0.0, vd = 0.0; int vn = 0;
        if (t >= off) { va = sa[t - off]; vd = sd[t - off]; vn = sn[t - off]; }
        __syncthreads();
        sa[t] += va; sd[t] += vd; sn[t] += vn;
        __syncthreads();
    }
    LA[t] = sa[t]; LDp[t] = sd[t]; NC[t] = sn[t];
}

// ---------------- phase 2b: build L_A, L_D (zero-padded lower-tri) ----------------
__global__ __launch_bounds__(256) void k_build(
    const double* __restrict__ LA, const double* __restrict__ LDp,
    const int* __restrict__ NC,
    float* __restrict__ Amat, float* __restrict__ Dmat)
{
    int idx = blockIdx.x * 256 + threadIdx.x;   // 0 .. N*N-1
    int u = idx >> 9;          // row
    int s = idx & (N - 1);     // col
    float va = 0.f, vd = 0.f;
    if (s <= u) {
        va = expf((float)(LA[u] - LA[s]));
        if ((NC[u] - NC[s]) & 1) va = -va;
        vd = expf((float)(LDp[u] - LDp[s]));
    }
    Amat[idx] = va;
    Dmat[idx] = vd;
}

// ---------------- phase 2c: beta = L_D @ L_A (lower-triangular 512^3 matmul) ----------------
__global__ __launch_bounds__(256) void k_betamm(
    const float* __restrict__ Dmat, const float* __restrict__ Amat,
    float* __restrict__ beta)
{
    const int bs = blockIdx.x;   // col tile
    const int bt = blockIdx.y;   // row tile
    if (bs > bt) return;

    __shared__ float sD[32][33];
    __shared__ float sA[32][33];

    const int tx = threadIdx.x & 31;
    const int ty = threadIdx.x >> 5;   // 0..7
    float acc[4] = {0.f, 0.f, 0.f, 0.f};

    for (int kt = bs; kt <= bt; kt++) {
        for (int i = threadIdx.x; i < 1024; i += 256) {
            int r = i >> 5, c = i & 31;
            sD[r][c] = Dmat[(bt * 32 + r) * N + kt * 32 + c];
            sA[r][c] = Amat[(kt * 32 + r) * N + bs * 32 + c];
        }
        __syncthreads();
#pragma unroll 8
        for (int k = 0; k < 32; k++) {
            float a = sA[k][tx];
#pragma unroll
            for (int j = 0; j < 4; j++)
                acc[j] += sD[ty + 8 * j][k] * a;
        }
        __syncthreads();
    }
#pragma unroll
    for (int j = 0; j < 4; j++)
        beta[(bt * 32 + ty + 8 * j) * N + bs * 32 + tx] = acc[j];
}

// ---------------- phase 3: one retrieval layer (attention-shaped) ----------------
__global__ __launch_bounds__(128) void k_phase3(
    const float* __restrict__ Xin, float* __restrict__ Xout,
    const float* __restrict__ Wl, const float* __restrict__ INSl,
    const float* __restrict__ ESl, const float* __restrict__ beta,
    int act)
{
    __shared__ float s_x[D];
    __shared__ float s_c[N];

    const int t = blockIdx.x;
    const int tid = threadIdx.x;

    s_x[tid] = Xin[t * D + tid];
    __syncthreads();

    for (int s = tid; s <= t; s += 128) {
        const float* ip = INSl + s * D;
        float acc = 0.f;
#pragma unroll 8
        for (int i = 0; i < D; i++) acc += s_x[i] * ip[i];
        s_c[s] = beta[t * N + s] * acc;
    }
    __syncthreads();

    float y = 0.f;
    const float* wp = Wl + tid;
#pragma unroll 4
    for (int i = 0; i < D; i++) y += s_x[i] * wp[i * D];
    const float* ep = ESl + tid;
    for (int s = 0; s <= t; s++) y += s_c[s] * ep[s * D];

    if (act) y = y * sigmoidf_(y);
    Xout[t * D + tid] = y;
}

extern "C" void kernel_launch(void* const* d_in, const int* in_sizes, int n_in,
                              void* d_out, int out_size, void* d_ws, size_t ws_size,
                              hipStream_t stream) {
    const float* seq     = (const float*)d_in[0];
    const float* W_mem   = (const float*)d_in[1];
    const float* W_q     = (const float*)d_in[2];
    const float* W_kv    = (const float*)d_in[3];
    const float* W_mom   = (const float*)d_in[4];
    const float* W_step  = (const float*)d_in[5];
    const float* W_decay = (const float*)d_in[6];
    float* out = (float*)d_out;

    float* ws   = (float*)d_ws;
    float* am   = ws;                  // N
    float* dec  = am + N;              // N
    float* Q    = dec + N;             // N*D
    float* INS  = Q + ND;              // 4*N*D
    float* ES   = INS + 4 * ND;        // 4*N*D
    float* beta = ES + 4 * ND;         // N*N
    float* X    = beta + N * N;        // N*D
    float* WT   = X + ND;              // 3*D*D
    float* Amat = WT + 3 * DD;         // N*N
    float* Dmat = Amat + N * N;        // N*N
    double* LA  = (double*)(Dmat + N * N);  // N doubles
    double* LDp = LA + N;                   // N doubles
    int* NC     = (int*)(LDp + N);          // N ints

    k_transpose<<<192, 256, 0, stream>>>(W_mem, WT);
    k_phase1<<<N, D, 0, stream>>>(seq, W_mem, W_q, W_kv, W_mom, W_step, W_decay,
                                  WT, Q, INS, ES, am, dec);
    k_logscan<<<1, N, 0, stream>>>(am, dec, LA, LDp, NC);
    k_build<<<(N * N) / 256, 256, 0, stream>>>(LA, LDp, NC, Amat, Dmat);
    dim3 mmgrid(N / 32, N / 32);
    k_betamm<<<mmgrid, 256, 0, stream>>>(Dmat, Amat, beta);

    k_phase3<<<N, D, 0, stream>>>(Q, X, W_mem + 0 * DD, INS + 0 * ND, ES + 0 * ND, beta, 1);
    k_phase3<<<N, D, 0, stream>>>(X, X, W_mem + 1 * DD, INS + 1 * ND, ES + 1 * ND, beta, 1);
    k_phase3<<<N, D, 0, stream>>>(X, X, W_mem + 2 * DD, INS + 2 * ND, ES + 2 * ND, beta, 1);
    k_phase3<<<N, D, 0, stream>>>(X, out, W_mem + 3 * DD, INS + 3 * ND, ES + 3 * ND, beta, 0);
}

// Round 3
// 181.197 us; speedup vs baseline: 1.9208x; 1.6485x over previous
//
#include <hip/hip_runtime.h>
#include <hip/hip_bf16.h>
#include <math.h>

#define N 512
#define D 128
#define DD (D*D)
#define ND (N*D)

__device__ __forceinline__ float sigmoidf_(float x) { return 1.f / (1.f + expf(-x)); }

// ---------------- transpose W_mem layers 1..3 for backward ----------------
__global__ void k_transpose(const float* __restrict__ W_mem, float* __restrict__ WT) {
    int idx = blockIdx.x * 256 + threadIdx.x;      // 0 .. 3*128*128-1
    int l = idx / DD;
    int r = idx % DD;
    int i = r / D;
    int j = r % D;
    WT[idx] = W_mem[(l + 1) * DD + j * D + i];
}

// ---------------- phase 1: per-token scalars, k/v/q, MLP fwd+bwd ----------------
// 512 threads: j = tid&127 (output col), p = tid>>7 (split-K part, 32 rows each)
__global__ __launch_bounds__(512) void k_phase1(
    const float* __restrict__ seq, const float* __restrict__ W_mem,
    const float* __restrict__ W_q, const float* __restrict__ W_kv,
    const float* __restrict__ W_mom, const float* __restrict__ W_step,
    const float* __restrict__ W_decay, const float* __restrict__ WT,
    float* __restrict__ Q, float* __restrict__ INS, float* __restrict__ ES,
    float* __restrict__ am, float* __restrict__ dec)
{
    __shared__ float s_seq[D], s_v[D], s_cur[D];
    __shared__ float s_h[4][D];
    __shared__ float s_part[4][D];
    __shared__ float s_p3[4][3][D];
    __shared__ float s_red[8];
    __shared__ float s_lr;

    const int t = blockIdx.x;
    const int tid = threadIdx.x;
    const int j = tid & 127;
    const int p = tid >> 7;
    const int i0 = p * 32;

    if (p == 0) s_seq[j] = seq[t * D + j];
    __syncthreads();

    // scalar dots: part1 -> W_step (lr), part2 -> W_mom (am), part3 -> W_decay
    float ps = 0.f;
    if (p == 1) ps = s_seq[j] * W_step[j];
    else if (p == 2) ps = s_seq[j] * W_mom[j];
    else if (p == 3) ps = s_seq[j] * W_decay[j];
#pragma unroll
    for (int off = 32; off > 0; off >>= 1) ps += __shfl_down(ps, off);
    if ((tid & 63) == 0) s_red[tid >> 6] = ps;
    __syncthreads();
    if (tid == 0) s_lr = s_red[2] + s_red[3];
    else if (tid == 1) am[t] = s_red[4] + s_red[5];
    else if (tid == 2) dec[t] = 1.f - sigmoidf_(s_red[6] + s_red[7]);

    // k, v, q split-K
    float kp = 0.f, vp = 0.f, qp = 0.f;
#pragma unroll 8
    for (int ii = 0; ii < 32; ii++) {
        int i = i0 + ii;
        float si = s_seq[i];
        kp += si * W_kv[i * 256 + j];
        vp += si * W_kv[i * 256 + 128 + j];
        qp += si * W_q[i * 128 + j];
    }
    s_p3[p][0][j] = kp; s_p3[p][1][j] = vp; s_p3[p][2][j] = qp;
    __syncthreads();
    if (p == 0) {
        float kj = s_p3[0][0][j] + s_p3[1][0][j] + s_p3[2][0][j] + s_p3[3][0][j];
        s_cur[j] = kj;
        INS[t * D + j] = kj;
    } else if (p == 1) {
        s_v[j] = s_p3[0][1][j] + s_p3[1][1][j] + s_p3[2][1][j] + s_p3[3][1][j];
    } else if (p == 2) {
        Q[t * D + j] = s_p3[0][2][j] + s_p3[1][2][j] + s_p3[2][2][j] + s_p3[3][2][j];
    }
    __syncthreads();

    // forward MLP
    for (int l = 0; l < 4; l++) {
        const float* Wl = W_mem + l * DD;
        float yp = 0.f;
#pragma unroll 8
        for (int ii = 0; ii < 32; ii++) {
            int i = i0 + ii;
            yp += s_cur[i] * Wl[i * D + j];
        }
        s_part[p][j] = yp;
        __syncthreads();
        if (p == 0) {
            float y = s_part[0][j] + s_part[1][j] + s_part[2][j] + s_part[3][j];
            s_h[l][j] = y;
            if (l < 3) {
                float a = y * sigmoidf_(y);
                s_cur[j] = a;
                INS[(l + 1) * ND + t * D + j] = a;
            }
        }
        __syncthreads();
    }

    // e3 = -lr * 2*(pred - v)/D
    if (p == 0) {
        float e = -s_lr * (2.f / (float)D) * (s_h[3][j] - s_v[j]);
        ES[3 * ND + t * D + j] = e;
        s_cur[j] = e;
    }
    __syncthreads();

    // backward
    for (int l = 3; l >= 1; l--) {
        const float* Wt = WT + (l - 1) * DD;
        float gp = 0.f;
#pragma unroll 8
        for (int ii = 0; ii < 32; ii++) {
            int i = i0 + ii;
            gp += s_cur[i] * Wt[i * D + j];
        }
        s_part[p][j] = gp;
        __syncthreads();
        if (p == 0) {
            float g = s_part[0][j] + s_part[1][j] + s_part[2][j] + s_part[3][j];
            float h = s_h[l - 1][j];
            float sg = sigmoidf_(h);
            float e2 = g * (sg * (1.f + h * (1.f - sg)));
            ES[(l - 1) * ND + t * D + j] = e2;
            s_cur[j] = e2;
        }
        __syncthreads();
    }
}

// ---------------- phase 2a: log-space prefix scans ----------------
__global__ __launch_bounds__(512) void k_logscan(
    const float* __restrict__ am, const float* __restrict__ dec,
    double* __restrict__ LA, double* __restrict__ LDp, int* __restrict__ NC)
{
    __shared__ double sa[N], sd[N];
    __shared__ int sn[N];
    const int t = threadIdx.x;
    float a = am[t];
    float d = dec[t];
    sa[t] = log((double)fmaxf(fabsf(a), 1e-38f));
    sd[t] = log((double)fmaxf(d, 1e-38f));
    sn[t] = (a < 0.f) ? 1 : 0;
    __syncthreads();
    for (int off = 1; off < N; off <<= 1) {
        double va = 0.0, vd = 0.0; int vn = 0;
        if (t >= off) { va = sa[t - off]; vd = sd[t - off]; vn = sn[t - off]; }
        __syncthreads();
        sa[t] += va; sd[t] += vd; sn[t] += vn;
        __syncthreads();
    }
    LA[t] = sa[t]; LDp[t] = sd[t]; NC[t] = sn[t];
}

// ---------------- phase 2b: build L_A, L_D ----------------
__global__ __launch_bounds__(256) void k_build(
    const double* __restrict__ LA, const double* __restrict__ LDp,
    const int* __restrict__ NC,
    float* __restrict__ Amat, float* __restrict__ Dmat)
{
    int idx = blockIdx.x * 256 + threadIdx.x;
    int u = idx >> 9;
    int s = idx & (N - 1);
    float va = 0.f, vd = 0.f;
    if (s <= u) {
        va = expf((float)(LA[u] - LA[s]));
        if ((NC[u] - NC[s]) & 1) va = -va;
        vd = expf((float)(LDp[u] - LDp[s]));
    }
    Amat[idx] = va;
    Dmat[idx] = vd;
}

// ---------------- phase 2c: beta = L_D @ L_A, split-K x4 + atomicAdd ----------------
__global__ __launch_bounds__(256) void k_betamm(
    const float* __restrict__ Dmat, const float* __restrict__ Amat,
    float* __restrict__ beta)
{
    const int bs = blockIdx.x;   // col tile
    const int bt = blockIdx.y;   // row tile
    const int z  = blockIdx.z;   // k chunk
    if (bs > bt) return;
    const int span = bt - bs + 1;
    const int chunk = (span + 3) >> 2;
    const int kBeg = bs + z * chunk;
    const int kEnd = (kBeg + chunk < bt + 1) ? (kBeg + chunk) : (bt + 1);
    if (kBeg >= kEnd) return;

    __shared__ float sD[32][33];
    __shared__ float sA[32][33];

    const int tx = threadIdx.x & 31;
    const int ty = threadIdx.x >> 5;
    float acc[4] = {0.f, 0.f, 0.f, 0.f};

    for (int kt = kBeg; kt < kEnd; kt++) {
        for (int i = threadIdx.x; i < 1024; i += 256) {
            int r = i >> 5, c = i & 31;
            sD[r][c] = Dmat[(bt * 32 + r) * N + kt * 32 + c];
            sA[r][c] = Amat[(kt * 32 + r) * N + bs * 32 + c];
        }
        __syncthreads();
#pragma unroll 8
        for (int k = 0; k < 32; k++) {
            float a = sA[k][tx];
#pragma unroll
            for (int j = 0; j < 4; j++)
                acc[j] += sD[ty + 8 * j][k] * a;
        }
        __syncthreads();
    }
#pragma unroll
    for (int j = 0; j < 4; j++)
        atomicAdd(&beta[(bt * 32 + ty + 8 * j) * N + bs * 32 + tx], acc[j]);
}

// ---------------- phase 3: all 4 retrieval layers fused, one block per token ----------------
__global__ __launch_bounds__(512) void k_phase3(
    const float* __restrict__ Q, float* __restrict__ out,
    const float* __restrict__ W_mem, const float* __restrict__ INS,
    const float* __restrict__ ES, const float* __restrict__ beta)
{
    __shared__ float s_x[D];
    __shared__ float s_c[N];
    __shared__ float s_part[4][D];

    const int t = blockIdx.x;
    const int tid = threadIdx.x;
    const int j = tid & 127;
    const int p = tid >> 7;
    const int i0 = p * 32;
    const int cnt = t + 1;
    const int chunk = (cnt + 3) >> 2;
    const int sBeg = p * chunk;
    const int sEnd = (sBeg + chunk < cnt) ? (sBeg + chunk) : cnt;
    const float brow = (tid <= t) ? beta[t * N + tid] : 0.f;

    if (p == 0) s_x[j] = Q[t * D + j];
    __syncthreads();

    for (int l = 0; l < 4; l++) {
        const float* INSl = INS + l * ND;
        const float* ESl  = ES + l * ND;
        const float* Wl   = W_mem + l * DD;

        // c_s = beta[t,s] * (x . in_s), one s per thread
        if (tid <= t) {
            const float4* ip = (const float4*)(INSl + tid * D);
            const float4* xp = (const float4*)s_x;
            float acc = 0.f;
#pragma unroll 8
            for (int i = 0; i < 32; i++) {
                float4 a = xp[i];
                float4 b = ip[i];
                acc += a.x * b.x + a.y * b.y + a.z * b.z + a.w * b.w;
            }
            s_c[tid] = brow * acc;
        }
        __syncthreads();

        // y_j = x@W[:,j] (split-K) + sum_s c_s * e_s[j] (split over s)
        float yp = 0.f;
#pragma unroll 4
        for (int s = sBeg; s < sEnd; s++) yp += s_c[s] * ESl[s * D + j];
#pragma unroll 8
        for (int ii = 0; ii < 32; ii++) {
            int i = i0 + ii;
            yp += s_x[i] * Wl[i * D + j];
        }
        s_part[p][j] = yp;
        __syncthreads();

        if (p == 0) {
            float y = s_part[0][j] + s_part[1][j] + s_part[2][j] + s_part[3][j];
            if (l < 3) {
                s_x[j] = y * sigmoidf_(y);
            } else {
                out[t * D + j] = y;
            }
        }
        __syncthreads();
    }
}

extern "C" void kernel_launch(void* const* d_in, const int* in_sizes, int n_in,
                              void* d_out, int out_size, void* d_ws, size_t ws_size,
                              hipStream_t stream) {
    const float* seq     = (const float*)d_in[0];
    const float* W_mem   = (const float*)d_in[1];
    const float* W_q     = (const float*)d_in[2];
    const float* W_kv    = (const float*)d_in[3];
    const float* W_mom   = (const float*)d_in[4];
    const float* W_step  = (const float*)d_in[5];
    const float* W_decay = (const float*)d_in[6];
    float* out = (float*)d_out;

    float* ws   = (float*)d_ws;
    float* am   = ws;                  // N
    float* dec  = am + N;              // N
    float* Q    = dec + N;             // N*D
    float* INS  = Q + ND;              // 4*N*D
    float* ES   = INS + 4 * ND;        // 4*N*D
    float* beta = ES + 4 * ND;         // N*N
    float* X    = beta + N * N;        // N*D (unused now)
    float* WT   = X + ND;              // 3*D*D
    float* Amat = WT + 3 * DD;         // N*N
    float* Dmat = Amat + N * N;        // N*N
    double* LA  = (double*)(Dmat + N * N);
    double* LDp = LA + N;
    int* NC     = (int*)(LDp + N);

    hipMemsetAsync(beta, 0, N * N * sizeof(float), stream);
    k_transpose<<<192, 256, 0, stream>>>(W_mem, WT);
    k_phase1<<<N, 512, 0, stream>>>(seq, W_mem, W_q, W_kv, W_mom, W_step, W_decay,
                                    WT, Q, INS, ES, am, dec);
    k_logscan<<<1, N, 0, stream>>>(am, dec, LA, LDp, NC);
    k_build<<<(N * N) / 256, 256, 0, stream>>>(LA, LDp, NC, Amat, Dmat);
    dim3 mmgrid(N / 32, N / 32, 4);
    k_betamm<<<mmgrid, 256, 0, stream>>>(Dmat, Amat, beta);
    k_phase3<<<N, 512, 0, stream>>>(Q, out, W_mem, INS, ES, beta);
}